// Round 9
// baseline (4548.513 us; speedup 1.0000x reference)
//
#include <hip/hip_runtime.h>

namespace {
constexpr int E_ = 512;
constexpr int H_ = 512;
constexpr int O_ = 32;
constexpr int B_ = 64;
constexpr int T_ = 512;
constexpr int RING = 8;
constexpr int FPAD = 16;                               // 64B per flag
// ws layout (floats)
constexpr size_t H0_OFF   = 0;                         // RING*B*H = 262144
constexpr size_t H1_OFF   = (size_t)RING * B_ * H_;    // 262144
constexpr size_t HF_OFF   = 2 * H1_OFF;                // 524288
constexpr size_t FLAG_OFF = HF_OFF + (size_t)B_ * H_;  // 557056
constexpr size_t FLAG_UINTS = 2u * 8u * 16u * FPAD;    // 4096
constexpr size_t WS_REQUIRED = (FLAG_OFF + FLAG_UINTS) * 4;
}

typedef float f32x4 __attribute__((ext_vector_type(4)));

// ---- weight row load: PLAIN cached loads, but via volatile asm so the
// compiler cannot rematerialize/sink them into the loop -> weights stay
// register-resident (r7 diagnostic: VGPR_Count=104 < 128 proved the C++
// loads were being re-streamed every step). Self-contained waitcnt. ----
__device__ __forceinline__ void wrow_load(const float* px, const float* ph,
                                          f32x4& x0, f32x4& x1, f32x4& h0, f32x4& h1) {
    asm volatile(
        "global_load_dwordx4 %0, %4, off\n\t"
        "global_load_dwordx4 %1, %4, off offset:1024\n\t"
        "global_load_dwordx4 %2, %5, off\n\t"
        "global_load_dwordx4 %3, %5, off offset:1024\n\t"
        "s_waitcnt vmcnt(0)"
        : "=&v"(x0), "=&v"(x1), "=&v"(h0), "=&v"(h1)
        : "v"(px), "v"(ph) : "memory");
}

// ---- coherent LLC ring load: 4 elems x 2 k-chunks (elem stride 2048B),
// self-contained (waitcnt inside; offsets <= 3072, 13-bit limit ok). ----
__device__ __forceinline__ void ring_load8(const float* p, f32x4 H[8]) {
    const float* p2 = p + 1024;   // +4096 B
    asm volatile(
        "global_load_dwordx4 %0, %8, off sc0 sc1\n\t"
        "global_load_dwordx4 %1, %8, off offset:1024 sc0 sc1\n\t"
        "global_load_dwordx4 %2, %8, off offset:2048 sc0 sc1\n\t"
        "global_load_dwordx4 %3, %8, off offset:3072 sc0 sc1\n\t"
        "global_load_dwordx4 %4, %9, off sc0 sc1\n\t"
        "global_load_dwordx4 %5, %9, off offset:1024 sc0 sc1\n\t"
        "global_load_dwordx4 %6, %9, off offset:2048 sc0 sc1\n\t"
        "global_load_dwordx4 %7, %9, off offset:3072 sc0 sc1\n\t"
        "s_waitcnt vmcnt(0)"
        : "=&v"(H[0]), "=&v"(H[1]), "=&v"(H[2]), "=&v"(H[3]),
          "=&v"(H[4]), "=&v"(H[5]), "=&v"(H[6]), "=&v"(H[7])
        : "v"(p), "v"(p2) : "memory");
}

__device__ __forceinline__ unsigned flag_poll(const unsigned* p) {
    unsigned v;
    asm volatile("global_load_dword %0, %1, off sc0 sc1\n\ts_waitcnt vmcnt(0)"
                 : "=&v"(v) : "v"(p) : "memory");
    return v;
}
__device__ __forceinline__ void vm_drain() {
    asm volatile("s_waitcnt vmcnt(0)" ::: "memory");
}
__device__ __forceinline__ void coh_store(float* p, float v) {
    asm volatile("global_store_dword %0, %1, off sc0 sc1" :: "v"(p), "v"(v) : "memory");
}
__device__ __forceinline__ void flag_store(unsigned* p, unsigned v) {
    asm volatile("global_store_dword %0, %1, off sc0 sc1" :: "v"(p), "v"(v) : "memory");
}

__device__ __forceinline__ float fast_tanh(float x) {
    float e = __builtin_amdgcn_exp2f(x * 2.885390081777927f);
    return 1.0f - 2.0f * __builtin_amdgcn_rcpf(e + 1.0f);
}

// pair-combine butterfly: v[8] partials/lane -> full sum of row (lane&7) on every lane
__device__ __forceinline__ float reduce8(const float v[8], int lane) {
    float a[4];
#pragma unroll
    for (int j = 0; j < 4; ++j) {
        const int sel = lane & 1;
        const float mine = sel ? v[2 * j + 1] : v[2 * j];
        const float send = sel ? v[2 * j] : v[2 * j + 1];
        a[j] = mine + __shfl_xor(send, 1, 64);
    }
    float b[2];
#pragma unroll
    for (int j = 0; j < 2; ++j) {
        const int sel = (lane >> 1) & 1;
        const float mine = sel ? a[2 * j + 1] : a[2 * j];
        const float send = sel ? a[2 * j] : a[2 * j + 1];
        b[j] = mine + __shfl_xor(send, 2, 64);
    }
    const int sel = (lane >> 2) & 1;
    const float mine = sel ? b[1] : b[0];
    const float send = sel ? b[0] : b[1];
    float s = mine + __shfl_xor(send, 4, 64);
    s += __shfl_xor(s, 8, 64);
    s += __shfl_xor(s, 16, 64);
    s += __shfl_xor(s, 32, 64);
    return s;
}

// =====================================================================
// 256 blocks = 2 layers x 8 groups(8 elems) x 16 chunks(32 rows); 8 waves;
// wave = 8 rows (wr=wid&3) x 4 elems (we=wid>>2). Block-cooperative sync
// (wave0 polls, 2 barriers/step). h-operands loaded per-wave to REGISTERS.
// Weights pinned in VGPRs via asm loads. L1 lookahead: h0(t) x-half runs
// before the poll barrier when last step's poll saw cnt0 >= t+2.
// =====================================================================
__global__ __launch_bounds__(512, 1) void rnn_pipe7(
    const int* __restrict__ x, const int* __restrict__ seq_lens,
    const float* __restrict__ emb,
    const float* __restrict__ Whx, const float* __restrict__ Whh,
    const float* __restrict__ b_h,
    float* __restrict__ h0_ring, float* __restrict__ h1_ring,
    float* __restrict__ h1_final, unsigned* __restrict__ flags)
{
    const int bid   = blockIdx.x;
    const int layer = bid >> 7;
    const int g     = (bid >> 4) & 7;
    const int c     = bid & 15;
    const int tid   = threadIdx.x;
    const int wid   = tid >> 6;
    const int lane  = tid & 63;
    const int we    = wid >> 2;          // elem quad (0..1)
    const int wr    = wid & 3;           // row octet
    const int rowbase = c * 32 + wr * 8;
    const int eg0   = g * 8 + we * 4;

    __shared__ float sx[2][4096];        // L0 emb double-buffer
    __shared__ unsigned s_la[2];         // L1 lookahead flag

    // ---- register-pinned weights ----
    const float* WxL = Whx + (size_t)layer * H_ * E_;
    const float* WhL = Whh + (size_t)layer * H_ * H_;
    f32x4 wx0[8], wx1[8], wh0[8], wh1[8];
#pragma unroll
    for (int r = 0; r < 8; ++r) {
        const int row = rowbase + r;
        wrow_load(WxL + (size_t)row * E_ + (lane << 2),
                  WhL + (size_t)row * H_ + (lane << 2),
                  wx0[r], wx1[r], wh0[r], wh1[r]);
    }
    const float bias = b_h[layer * H_ + rowbase + (lane & 7)];

    int sl4[4];
#pragma unroll
    for (int q = 0; q < 4; ++q) sl4[q] = seq_lens[eg0 + q];
    int Tg = 1;
#pragma unroll
    for (int j = 0; j < 8; ++j) {
        const int s = seq_lens[g * 8 + j];
        Tg = s > Tg ? s : Tg;
    }

    unsigned* const myflag = flags + ((size_t)((layer * 8 + g) * 16 + c)) * FPAD;
    const unsigned* pollp = flags + ((size_t)((0 * 8 + g) * 16 + (lane & 15))) * FPAD;
    if (lane >= 16 && lane < 32)
        pollp = flags + ((size_t)((8 + g) * 16 + (lane - 16))) * FPAD;

    const int se  = wid;                 // staging elem for sx (L0)
    const int seg = g * 8 + se;

    long budget = 1l << 24;

    if (layer == 0) {
        // prologue: stage x(0), 16B-stride conflict-free pattern
        {
            const int tok = x[(size_t)seg * T_];
            *(f32x4*)&sx[0][(se << 9) + (lane << 2)] =
                *(const f32x4*)(emb + ((size_t)tok << 9) + (lane << 2));
            *(f32x4*)&sx[0][(se << 9) + 256 + (lane << 2)] =
                *(const f32x4*)(emb + ((size_t)tok << 9) + 256 + (lane << 2));
        }
        __syncthreads();

        for (int t = 0; t < Tg; ++t) {
            const int cur = t & 1, slot = t & 7, pslot = (t - 1) & 7;
            float vvp[4][8];

            // ---- phase A: emb-half ----
#pragma unroll
            for (int q = 0; q < 4; ++q) {
                if (t >= sl4[q]) continue;
                const int el = (we << 2) + q;
                const f32x4 lx0 = *(const f32x4*)&sx[cur][(el << 9) + (lane << 2)];
                const f32x4 lx1 = *(const f32x4*)&sx[cur][(el << 9) + 256 + (lane << 2)];
#pragma unroll
                for (int r = 0; r < 8; ++r) {
                    float s = wx0[r][0] * lx0[0];
                    s = fmaf(wx0[r][1], lx0[1], s);
                    s = fmaf(wx0[r][2], lx0[2], s);
                    s = fmaf(wx0[r][3], lx0[3], s);
                    s = fmaf(wx1[r][0], lx1[0], s);
                    s = fmaf(wx1[r][1], lx1[1], s);
                    s = fmaf(wx1[r][2], lx1[2], s);
                    s = fmaf(wx1[r][3], lx1[3], s);
                    vvp[q][r] = s;
                }
            }
            // prefetch x(t+1)
            f32x4 px0, px1;
            const bool havepf = (t + 1 < Tg);
            if (havepf) {
                const int tok = x[(size_t)seg * T_ + t + 1];
                px0 = *(const f32x4*)(emb + ((size_t)tok << 9) + (lane << 2));
                px1 = *(const f32x4*)(emb + ((size_t)tok << 9) + 256 + (lane << 2));
            }
            // poll: cnt0 >= t (h0(t-1) done), cnt1 >= t-7 (ring backpressure)
            if (wid == 0 && t > 0) {
                const int tgt = (lane < 16) ? t : ((lane < 32) ? t - 7 : 0);
                for (;;) {
                    const unsigned v = flag_poll(pollp);
                    if (!__any((int)v < tgt)) break;
                    if (--budget < 0) break;
                }
            }
            __syncthreads();

            // ---- phase B: per-wave reg load of h0(t-1), h-half, epilogue ----
            f32x4 H[8];
            if (t > 0) {
                ring_load8(h0_ring + (((size_t)pslot << 6) + eg0) * 512 + (lane << 2), H);
            } else {
#pragma unroll
                for (int i = 0; i < 8; ++i) H[i] = 0;
            }
#pragma unroll
            for (int q = 0; q < 4; ++q) {
                if (t >= sl4[q]) continue;
#pragma unroll
                for (int r = 0; r < 8; ++r) {
                    float s = vvp[q][r];
                    s = fmaf(wh0[r][0], H[2 * q][0], s);
                    s = fmaf(wh0[r][1], H[2 * q][1], s);
                    s = fmaf(wh0[r][2], H[2 * q][2], s);
                    s = fmaf(wh0[r][3], H[2 * q][3], s);
                    s = fmaf(wh1[r][0], H[2 * q + 1][0], s);
                    s = fmaf(wh1[r][1], H[2 * q + 1][1], s);
                    s = fmaf(wh1[r][2], H[2 * q + 1][2], s);
                    s = fmaf(wh1[r][3], H[2 * q + 1][3], s);
                    vvp[q][r] = s;
                }
                const float sum = reduce8(vvp[q], lane);
                const float hv = fast_tanh(sum + bias);
                if (lane < 8)
                    coh_store(h0_ring + (((size_t)slot << 6) + eg0 + q) * 512 + rowbase + lane, hv);
            }
            if (havepf) {
                *(f32x4*)&sx[cur ^ 1][(se << 9) + (lane << 2)] = px0;
                *(f32x4*)&sx[cur ^ 1][(se << 9) + 256 + (lane << 2)] = px1;
            }
            vm_drain();
            __syncthreads();
            if (tid == 0) flag_store(myflag, (unsigned)(t + 1));
        }
    } else {
        // ---- layer 1 ----
        if (tid == 0) { s_la[0] = 0; s_la[1] = 0; }
        __syncthreads();

        for (int t = 0; t < Tg; ++t) {
            const int slot = t & 7, pslot = (t - 1) & 7;
            float vvp[4][8];
            f32x4 Hx[8];

            // ---- phase A: lookahead x-half on h0(t) if confirmed last step ----
            const bool la = (t > 0) && (s_la[t & 1] != 0u);
            bool have_x = false;
            if (la) {
                ring_load8(h0_ring + (((size_t)slot << 6) + eg0) * 512 + (lane << 2), Hx);
#pragma unroll
                for (int q = 0; q < 4; ++q) {
                    if (t >= sl4[q]) continue;
#pragma unroll
                    for (int r = 0; r < 8; ++r) {
                        float s = wx0[r][0] * Hx[2 * q][0];
                        s = fmaf(wx0[r][1], Hx[2 * q][1], s);
                        s = fmaf(wx0[r][2], Hx[2 * q][2], s);
                        s = fmaf(wx0[r][3], Hx[2 * q][3], s);
                        s = fmaf(wx1[r][0], Hx[2 * q + 1][0], s);
                        s = fmaf(wx1[r][1], Hx[2 * q + 1][1], s);
                        s = fmaf(wx1[r][2], Hx[2 * q + 1][2], s);
                        s = fmaf(wx1[r][3], Hx[2 * q + 1][3], s);
                        vvp[q][r] = s;
                    }
                }
                have_x = true;
            }
            // poll: cnt0 >= t+1 (h0(t) done), cnt1 >= t (h1(t-1) done); lookahead cnt0 >= t+2
            if (wid == 0) {
                const int tgt = (lane < 16) ? t + 1 : ((lane < 32) ? t : 0);
                unsigned v = 0;
                for (;;) {
                    v = flag_poll(pollp);
                    if (!__any((int)v < tgt)) break;
                    if (--budget < 0) break;
                }
                const bool la_next = !__any((lane < 16) && ((int)v < t + 2));
                if (lane == 0) s_la[(t + 1) & 1] = la_next ? 1u : 0u;
            }
            __syncthreads();

            // ---- phase B ----
            if (!have_x) {
                ring_load8(h0_ring + (((size_t)slot << 6) + eg0) * 512 + (lane << 2), Hx);
#pragma unroll
                for (int q = 0; q < 4; ++q) {
                    if (t >= sl4[q]) continue;
#pragma unroll
                    for (int r = 0; r < 8; ++r) {
                        float s = wx0[r][0] * Hx[2 * q][0];
                        s = fmaf(wx0[r][1], Hx[2 * q][1], s);
                        s = fmaf(wx0[r][2], Hx[2 * q][2], s);
                        s = fmaf(wx0[r][3], Hx[2 * q][3], s);
                        s = fmaf(wx1[r][0], Hx[2 * q + 1][0], s);
                        s = fmaf(wx1[r][1], Hx[2 * q + 1][1], s);
                        s = fmaf(wx1[r][2], Hx[2 * q + 1][2], s);
                        s = fmaf(wx1[r][3], Hx[2 * q + 1][3], s);
                        vvp[q][r] = s;
                    }
                }
            }
            if (t > 0) {
                f32x4 H1[8];
                ring_load8(h1_ring + (((size_t)pslot << 6) + eg0) * 512 + (lane << 2), H1);
#pragma unroll
                for (int q = 0; q < 4; ++q) {
                    if (t >= sl4[q]) continue;
#pragma unroll
                    for (int r = 0; r < 8; ++r) {
                        float s = vvp[q][r];
                        s = fmaf(wh0[r][0], H1[2 * q][0], s);
                        s = fmaf(wh0[r][1], H1[2 * q][1], s);
                        s = fmaf(wh0[r][2], H1[2 * q][2], s);
                        s = fmaf(wh0[r][3], H1[2 * q][3], s);
                        s = fmaf(wh1[r][0], H1[2 * q + 1][0], s);
                        s = fmaf(wh1[r][1], H1[2 * q + 1][1], s);
                        s = fmaf(wh1[r][2], H1[2 * q + 1][2], s);
                        s = fmaf(wh1[r][3], H1[2 * q + 1][3], s);
                        vvp[q][r] = s;
                    }
                }
            }
#pragma unroll
            for (int q = 0; q < 4; ++q) {
                if (t >= sl4[q]) continue;
                const float sum = reduce8(vvp[q], lane);
                const float hv = fast_tanh(sum + bias);
                if (lane < 8) {
                    coh_store(h1_ring + (((size_t)slot << 6) + eg0 + q) * 512 + rowbase + lane, hv);
                    if (t == sl4[q] - 1)
                        h1_final[((size_t)(eg0 + q) << 9) + rowbase + lane] = hv;
                }
            }
            vm_drain();
            __syncthreads();
            if (tid == 0) flag_store(myflag, (unsigned)(t + 1));
        }
    }
}

// ---- final head: y = Wyh[1] @ h1 + b_y[1]; out = Wf @ y + bf ----
__device__ __forceinline__ float dot4(float4 a, float4 b) {
    return fmaf(a.x, b.x, fmaf(a.y, b.y, fmaf(a.z, b.z, a.w * b.w)));
}
__device__ __forceinline__ float wave_reduce(float acc) {
#pragma unroll
    for (int off = 32; off > 0; off >>= 1) acc += __shfl_down(acc, off, 64);
    return acc;
}

__global__ __launch_bounds__(512) void head_kernel(
    const float* __restrict__ h1f, const float* __restrict__ Wyh,
    const float* __restrict__ b_y, const float* __restrict__ Wf,
    const float* __restrict__ bf, float* __restrict__ out)
{
    const int e = blockIdx.x;
    const int tid = threadIdx.x, wid = tid >> 6, lane = tid & 63;
    const int k0 = lane << 3;
    __shared__ float sh[H_];
    __shared__ float sy[H_];
    sh[tid] = h1f[(size_t)e * H_ + tid];
    __syncthreads();
    const float4 hA = *(const float4*)&sh[k0];
    const float4 hB = *(const float4*)&sh[k0 + 4];
    const float* Wy1 = Wyh + H_ * H_;
#pragma unroll 4
    for (int rr = 0; rr < 64; ++rr) {
        const int row = (wid << 6) + rr;
        float acc = wave_reduce(dot4(*(const float4*)&Wy1[(size_t)row * H_ + k0], hA) +
                                dot4(*(const float4*)&Wy1[(size_t)row * H_ + k0 + 4], hB));
        if (lane == 0) sy[row] = acc + b_y[H_ + row];
    }
    __syncthreads();
    const float4 yA = *(const float4*)&sy[k0];
    const float4 yB = *(const float4*)&sy[k0 + 4];
#pragma unroll
    for (int rr = 0; rr < 4; ++rr) {
        const int o = (wid << 2) + rr;
        float acc = wave_reduce(dot4(*(const float4*)&Wf[(size_t)o * H_ + k0], yA) +
                                dot4(*(const float4*)&Wf[(size_t)o * H_ + k0 + 4], yB));
        if (lane == 0) out[(size_t)e * O_ + o] = acc + bf[o];
    }
}

// ---- fallback (round-0, known-passing) ----
__global__ __launch_bounds__(1024, 1) void rnn_fused_fb(
    const int* __restrict__ x, const int* __restrict__ seq_lens,
    const float* __restrict__ emb, const float* __restrict__ Whx,
    const float* __restrict__ Whh, const float* __restrict__ b_h,
    const float* __restrict__ Wyh, const float* __restrict__ b_y,
    const float* __restrict__ Wf, const float* __restrict__ bf,
    float* __restrict__ out)
{
    const int b = blockIdx.x, tid = threadIdx.x;
    const int wave = tid >> 6, lane = tid & 63, k0 = lane << 3;
    __shared__ float s_inp[E_];
    __shared__ float s_h0[2][H_];
    __shared__ float s_h1[2][H_];
    __shared__ float s_y[H_];
    if (tid < H_) { s_h0[0][tid]=0.f; s_h0[1][tid]=0.f; s_h1[0][tid]=0.f; s_h1[1][tid]=0.f; }
    const int Tb = seq_lens[b];
    const float* Whx0 = Whx; const float* Whx1 = Whx + H_*E_;
    const float* Whh0 = Whh; const float* Whh1 = Whh + H_*H_;
    for (int t = 0; t < Tb; ++t) {
        const int cur = t & 1, prv = cur ^ 1;
        if (tid < E_) { const int tok = x[b*T_+t]; s_inp[tid] = emb[(size_t)tok*E_+tid]; }
        __syncthreads();
        const float4 iA = *(const float4*)&s_inp[k0], iB = *(const float4*)&s_inp[k0+4];
        const float4 pA = *(const float4*)&s_h0[prv][k0], pB = *(const float4*)&s_h0[prv][k0+4];
#pragma unroll 4
        for (int r = 0; r < 32; ++r) {
            const int i = (wave<<5)+r;
            float acc = dot4(*(const float4*)&Whx0[i*E_+k0], iA) + dot4(*(const float4*)&Whx0[i*E_+k0+4], iB)
                      + dot4(*(const float4*)&Whh0[i*H_+k0], pA) + dot4(*(const float4*)&Whh0[i*H_+k0+4], pB);
            acc = wave_reduce(acc);
            if (lane == 0) s_h0[cur][i] = tanhf(acc + b_h[i]);
        }
        __syncthreads();
        const float4 cA = *(const float4*)&s_h0[cur][k0], cB = *(const float4*)&s_h0[cur][k0+4];
        const float4 qA = *(const float4*)&s_h1[prv][k0], qB = *(const float4*)&s_h1[prv][k0+4];
#pragma unroll 4
        for (int r = 0; r < 32; ++r) {
            const int i = (wave<<5)+r;
            float acc = dot4(*(const float4*)&Whx1[i*E_+k0], cA) + dot4(*(const float4*)&Whx1[i*E_+k0+4], cB)
                      + dot4(*(const float4*)&Whh1[i*H_+k0], qA) + dot4(*(const float4*)&Whh1[i*H_+k0+4], qB);
            acc = wave_reduce(acc);
            if (lane == 0) s_h1[cur][i] = tanhf(acc + b_h[H_+i]);
        }
        __syncthreads();
    }
    const int lastb = (Tb-1) & 1;
    const float4 hA = *(const float4*)&s_h1[lastb][k0], hB = *(const float4*)&s_h1[lastb][k0+4];
    const float* Wy1 = Wyh + H_*H_;
#pragma unroll 4
    for (int r = 0; r < 32; ++r) {
        const int i = (wave<<5)+r;
        float acc = wave_reduce(dot4(*(const float4*)&Wy1[i*H_+k0], hA) + dot4(*(const float4*)&Wy1[i*H_+k0+4], hB));
        if (lane == 0) s_y[i] = acc + b_y[H_+i];
    }
    __syncthreads();
    const float4 yA = *(const float4*)&s_y[k0], yB = *(const float4*)&s_y[k0+4];
    if (wave < 8) {
#pragma unroll
        for (int r = 0; r < 4; ++r) {
            const int o = (wave<<2)+r;
            float acc = wave_reduce(dot4(*(const float4*)&Wf[o*H_+k0], yA) + dot4(*(const float4*)&Wf[o*H_+k0+4], yB));
            if (lane == 0) out[b*O_+o] = acc + bf[o];
        }
    }
}

extern "C" void kernel_launch(void* const* d_in, const int* in_sizes, int n_in,
                              void* d_out, int out_size, void* d_ws, size_t ws_size,
                              hipStream_t stream) {
    const int*   x    = (const int*)d_in[0];
    const int*   sl   = (const int*)d_in[1];
    const float* emb  = (const float*)d_in[2];
    const float* Whx  = (const float*)d_in[3];
    const float* Whh  = (const float*)d_in[4];
    const float* b_h  = (const float*)d_in[5];
    const float* Wyh  = (const float*)d_in[6];
    const float* b_y  = (const float*)d_in[7];
    const float* Wf   = (const float*)d_in[8];
    const float* bf   = (const float*)d_in[9];
    float* out = (float*)d_out;

    if (ws_size < WS_REQUIRED) {
        rnn_fused_fb<<<B_, 1024, 0, stream>>>(x, sl, emb, Whx, Whh, b_h, Wyh, b_y, Wf, bf, out);
        return;
    }

    float* ws_f = (float*)d_ws;
    float* h0_ring = ws_f + H0_OFF;
    float* h1_ring = ws_f + H1_OFF;
    float* h1f     = ws_f + HF_OFF;
    unsigned* flags = (unsigned*)(ws_f + FLAG_OFF);

    hipMemsetAsync(flags, 0, FLAG_UINTS * sizeof(unsigned), stream);
    rnn_pipe7<<<256, 512, 0, stream>>>(x, sl, emb, Whx, Whh, b_h,
                                       h0_ring, h1_ring, h1f, flags);
    head_kernel<<<B_, 512, 0, stream>>>(h1f, Wyh, b_y, Wf, bf, out);
}

// Round 10
// 1952.968 us; speedup vs baseline: 2.3290x; 2.3290x over previous
//
#include <hip/hip_runtime.h>

namespace {
constexpr int E_ = 512;
constexpr int H_ = 512;
constexpr int O_ = 32;
constexpr int B_ = 64;
constexpr int T_ = 512;
constexpr int RING = 8;
constexpr int FPAD = 16;                               // 64B per flag
// ws layout (floats)
constexpr size_t H0_OFF   = 0;                         // RING*B*H = 262144
constexpr size_t H1_OFF   = (size_t)RING * B_ * H_;    // 262144
constexpr size_t HF_OFF   = 2 * H1_OFF;                // 524288
constexpr size_t FLAG_OFF = HF_OFF + (size_t)B_ * H_;  // 557056
constexpr size_t FLAG_UINTS = 2u * 8u * 32u * FPAD;    // 8192
constexpr size_t WS_REQUIRED = (FLAG_OFF + FLAG_UINTS) * 4;  // 2,260,992 B
}

typedef float f32x4 __attribute__((ext_vector_type(4)));

// ---- coherent LLC primitives; self-contained (waitcnt inside asm) ----
// load elem slice: p and p+1024B (k-chunk stride 256 floats)
__device__ __forceinline__ void coh_ld2k(const float* p, f32x4& a, f32x4& b) {
    asm volatile(
        "global_load_dwordx4 %0, %2, off sc0 sc1\n\t"
        "global_load_dwordx4 %1, %2, off offset:1024 sc0 sc1\n\t"
        "s_waitcnt vmcnt(0)"
        : "=&v"(a), "=&v"(b) : "v"(p) : "memory");
}
__device__ __forceinline__ void coh_ld4k(const float* p, const float* q,
                                         f32x4& a, f32x4& b, f32x4& c, f32x4& d) {
    asm volatile(
        "global_load_dwordx4 %0, %4, off sc0 sc1\n\t"
        "global_load_dwordx4 %1, %4, off offset:1024 sc0 sc1\n\t"
        "global_load_dwordx4 %2, %5, off sc0 sc1\n\t"
        "global_load_dwordx4 %3, %5, off offset:1024 sc0 sc1\n\t"
        "s_waitcnt vmcnt(0)"
        : "=&v"(a), "=&v"(b), "=&v"(c), "=&v"(d) : "v"(p), "v"(q) : "memory");
}
__device__ __forceinline__ unsigned flag_poll(const unsigned* p) {
    unsigned v;
    asm volatile("global_load_dword %0, %1, off sc0 sc1\n\ts_waitcnt vmcnt(0)"
                 : "=&v"(v) : "v"(p) : "memory");
    return v;
}
__device__ __forceinline__ void vm_drain() {
    asm volatile("s_waitcnt vmcnt(0)" ::: "memory");
}
__device__ __forceinline__ void coh_store(float* p, float v) {
    asm volatile("global_store_dword %0, %1, off sc0 sc1" :: "v"(p), "v"(v) : "memory");
}
__device__ __forceinline__ void flag_store(unsigned* p, unsigned v) {
    asm volatile("global_store_dword %0, %1, off sc0 sc1" :: "v"(p), "v"(v) : "memory");
}

__device__ __forceinline__ float fast_tanh(float x) {
    float e = __builtin_amdgcn_exp2f(x * 2.885390081777927f);
    return 1.0f - 2.0f * __builtin_amdgcn_rcpf(e + 1.0f);
}

// pair-combine butterfly: v[4] partials/lane -> full sum of row (lane&3) on every lane
__device__ __forceinline__ float reduce4(const float v[4], int lane) {
    float a[2];
#pragma unroll
    for (int j = 0; j < 2; ++j) {
        const int sel = lane & 1;
        const float mine = sel ? v[2 * j + 1] : v[2 * j];
        const float send = sel ? v[2 * j] : v[2 * j + 1];
        a[j] = mine + __shfl_xor(send, 1, 64);
    }
    const int sel = (lane >> 1) & 1;
    const float mine = sel ? a[1] : a[0];
    const float send = sel ? a[0] : a[1];
    float s = mine + __shfl_xor(send, 2, 64);
    s += __shfl_xor(s, 4, 64);
    s += __shfl_xor(s, 8, 64);
    s += __shfl_xor(s, 16, 64);
    s += __shfl_xor(s, 32, 64);
    return s;
}

// =====================================================================
// 512 blocks = 2 layers x 8 groups(8 elems) x 32 chunks(16 rows); 8 waves;
// wave = 4 rows (wr=wid&3) x 4 elems (we=wid>>2). __launch_bounds__(512,4)
// caps VGPR at 128 -> 2 blocks/CU co-resident (512 blocks on 256 CUs) and
// the 64-float/lane weight set FITS in registers (r8 lesson: at 8 rows/wave
// the 128-float set cannot be held; forcing it via asm spilled to scratch,
// FETCH 0.5->1.5GB). Block-cooperative sync: wave0 polls 64 flags
// lane-parallel, LDS-staged h at 16B lane stride (conflict-free).
// =====================================================================
__global__ __launch_bounds__(512, 4) void rnn_pipe8(
    const int* __restrict__ x, const int* __restrict__ seq_lens,
    const float* __restrict__ emb,
    const float* __restrict__ Whx, const float* __restrict__ Whh,
    const float* __restrict__ b_h,
    float* __restrict__ h0_ring, float* __restrict__ h1_ring,
    float* __restrict__ h1_final, unsigned* __restrict__ flags)
{
    const int bid   = blockIdx.x;
    const int layer = bid >> 8;          // 0..1
    const int g     = (bid >> 5) & 7;    // group of 8 elems
    const int c     = bid & 31;          // chunk of 16 rows
    const int tid   = threadIdx.x;
    const int wid   = tid >> 6;
    const int lane  = tid & 63;
    const int we    = wid >> 2;          // elem quad (0..1)
    const int wr    = wid & 3;           // row quad (0..3)
    const int rowbase = c * 16 + wr * 4;
    const int eg0   = g * 8 + we * 4;

    __shared__ float sx[2][4096];        // L0 emb double-buffer
    __shared__ float sh[4096];           // h0 operand
    __shared__ float sh1[4096];          // L1: h1(t-1)

    // ---- weights (plain loads; live set ~110 regs fits under the 128 cap) ----
    const float* WxL = Whx + (size_t)layer * H_ * E_;
    const float* WhL = Whh + (size_t)layer * H_ * H_;
    f32x4 wx0[4], wx1[4], wh0[4], wh1[4];
#pragma unroll
    for (int r = 0; r < 4; ++r) {
        const int row = rowbase + r;
        wx0[r] = *(const f32x4*)(WxL + (size_t)row * E_ + (lane << 2));
        wx1[r] = *(const f32x4*)(WxL + (size_t)row * E_ + 256 + (lane << 2));
        wh0[r] = *(const f32x4*)(WhL + (size_t)row * H_ + (lane << 2));
        wh1[r] = *(const f32x4*)(WhL + (size_t)row * H_ + 256 + (lane << 2));
    }
    const float bias = b_h[layer * H_ + rowbase + (lane & 3)];

    int sl4[4];
#pragma unroll
    for (int q = 0; q < 4; ++q) sl4[q] = seq_lens[eg0 + q];
    int Tg = 1;
#pragma unroll
    for (int j = 0; j < 8; ++j) {
        const int s = seq_lens[g * 8 + j];
        Tg = s > Tg ? s : Tg;
    }

    // flags: [2][8][32] x FPAD. Wave0: lanes 0..31 watch L0 set, 32..63 L1 set.
    unsigned* const myflag = flags + ((size_t)((layer * 8 + g) * 32 + c)) * FPAD;
    const unsigned* const pollp = (lane < 32)
        ? flags + ((size_t)(g * 32 + lane)) * FPAD
        : flags + ((size_t)((8 + g) * 32 + (lane - 32))) * FPAD;

    const int se  = wid;                 // staging elem = wave id
    const int seg = g * 8 + se;

    long budget = 1l << 24;

    if (layer == 0) {
        // prologue: stage x(0) at 16B lane stride (conflict-free)
        {
            const int tok = x[(size_t)seg * T_];
            *(f32x4*)&sx[0][(se << 9) + (lane << 2)] =
                *(const f32x4*)(emb + ((size_t)tok << 9) + (lane << 2));
            *(f32x4*)&sx[0][(se << 9) + 256 + (lane << 2)] =
                *(const f32x4*)(emb + ((size_t)tok << 9) + 256 + (lane << 2));
        }
        __syncthreads();

        for (int t = 0; t < Tg; ++t) {
            const int cur = t & 1, slot = t & 7, pslot = (t - 1) & 7;
            float vvp[4][4];

            // ---- phase A: emb-half (no dependency on poll) ----
#pragma unroll
            for (int q = 0; q < 4; ++q) {
                if (t >= sl4[q]) continue;
                const int el = (we << 2) + q;
                const f32x4 lx0 = *(const f32x4*)&sx[cur][(el << 9) + (lane << 2)];
                const f32x4 lx1 = *(const f32x4*)&sx[cur][(el << 9) + 256 + (lane << 2)];
#pragma unroll
                for (int r = 0; r < 4; ++r) {
                    float s = wx0[r][0] * lx0[0];
                    s = fmaf(wx0[r][1], lx0[1], s);
                    s = fmaf(wx0[r][2], lx0[2], s);
                    s = fmaf(wx0[r][3], lx0[3], s);
                    s = fmaf(wx1[r][0], lx1[0], s);
                    s = fmaf(wx1[r][1], lx1[1], s);
                    s = fmaf(wx1[r][2], lx1[2], s);
                    s = fmaf(wx1[r][3], lx1[3], s);
                    vvp[q][r] = s;
                }
            }
            // prefetch x(t+1) (plain cached loads)
            f32x4 px0, px1;
            const bool havepf = (t + 1 < Tg);
            if (havepf) {
                const int tok = x[(size_t)seg * T_ + t + 1];
                px0 = *(const f32x4*)(emb + ((size_t)tok << 9) + (lane << 2));
                px1 = *(const f32x4*)(emb + ((size_t)tok << 9) + 256 + (lane << 2));
            }
            // poll: lanes<32: cnt0 >= t (h0(t-1) done); lanes>=32: cnt1 >= t-7
            if (wid == 0 && t > 0) {
                const int tgt = (lane < 32) ? t : t - 7;
                for (;;) {
                    const unsigned v = flag_poll(pollp);
                    if (!__any((int)v < tgt)) break;
                    if (--budget < 0) break;
                }
            }
            __syncthreads();

            // ---- stage h0(t-1) -> sh (16B lane stride) ----
            if (t > 0) {
                f32x4 a, b;
                coh_ld2k(h0_ring + (((size_t)pslot << 6) + seg) * 512 + (lane << 2), a, b);
                *(f32x4*)&sh[(se << 9) + (lane << 2)] = a;
                *(f32x4*)&sh[(se << 9) + 256 + (lane << 2)] = b;
            } else {
                f32x4 z = 0;
                *(f32x4*)&sh[(se << 9) + (lane << 2)] = z;
                *(f32x4*)&sh[(se << 9) + 256 + (lane << 2)] = z;
            }
            __syncthreads();

            // ---- phase B: h-half + epilogue ----
#pragma unroll
            for (int q = 0; q < 4; ++q) {
                if (t >= sl4[q]) continue;
                const int el = (we << 2) + q;
                const f32x4 h0a = *(const f32x4*)&sh[(el << 9) + (lane << 2)];
                const f32x4 h0b = *(const f32x4*)&sh[(el << 9) + 256 + (lane << 2)];
#pragma unroll
                for (int r = 0; r < 4; ++r) {
                    float s = vvp[q][r];
                    s = fmaf(wh0[r][0], h0a[0], s);
                    s = fmaf(wh0[r][1], h0a[1], s);
                    s = fmaf(wh0[r][2], h0a[2], s);
                    s = fmaf(wh0[r][3], h0a[3], s);
                    s = fmaf(wh1[r][0], h0b[0], s);
                    s = fmaf(wh1[r][1], h0b[1], s);
                    s = fmaf(wh1[r][2], h0b[2], s);
                    s = fmaf(wh1[r][3], h0b[3], s);
                    vvp[q][r] = s;
                }
                const float sum = reduce4(vvp[q], lane);
                const float hv = fast_tanh(sum + bias);
                if (lane < 4)
                    coh_store(h0_ring + (((size_t)slot << 6) + eg0 + q) * 512 + rowbase + lane, hv);
            }
            if (havepf) {
                *(f32x4*)&sx[cur ^ 1][(se << 9) + (lane << 2)] = px0;
                *(f32x4*)&sx[cur ^ 1][(se << 9) + 256 + (lane << 2)] = px1;
            }
            vm_drain();
            __syncthreads();
            if (tid == 0) flag_store(myflag, (unsigned)(t + 1));
        }
    } else {
        // ---- layer 1 ----
        for (int t = 0; t < Tg; ++t) {
            const int slot = t & 7, pslot = (t - 1) & 7;
            float vvp[4][4];

            // poll: lanes<32: cnt0 >= t+1 (h0(t) done); lanes>=32: cnt1 >= t
            if (wid == 0) {
                const int tgt = (lane < 32) ? t + 1 : t;
                for (;;) {
                    const unsigned v = flag_poll(pollp);
                    if (!__any((int)v < tgt)) break;
                    if (--budget < 0) break;
                }
            }
            __syncthreads();

            // stage h0(t)->sh, h1(t-1)->sh1
            if (t > 0) {
                f32x4 a, b, cc, d;
                coh_ld4k(h0_ring + (((size_t)slot << 6) + seg) * 512 + (lane << 2),
                         h1_ring + (((size_t)pslot << 6) + seg) * 512 + (lane << 2),
                         a, b, cc, d);
                *(f32x4*)&sh[(se << 9) + (lane << 2)] = a;
                *(f32x4*)&sh[(se << 9) + 256 + (lane << 2)] = b;
                *(f32x4*)&sh1[(se << 9) + (lane << 2)] = cc;
                *(f32x4*)&sh1[(se << 9) + 256 + (lane << 2)] = d;
            } else {
                f32x4 a, b;
                coh_ld2k(h0_ring + (((size_t)slot << 6) + seg) * 512 + (lane << 2), a, b);
                *(f32x4*)&sh[(se << 9) + (lane << 2)] = a;
                *(f32x4*)&sh[(se << 9) + 256 + (lane << 2)] = b;
                f32x4 z = 0;
                *(f32x4*)&sh1[(se << 9) + (lane << 2)] = z;
                *(f32x4*)&sh1[(se << 9) + 256 + (lane << 2)] = z;
            }
            __syncthreads();

#pragma unroll
            for (int q = 0; q < 4; ++q) {
                if (t >= sl4[q]) continue;
                const int el = (we << 2) + q;
                const f32x4 xa = *(const f32x4*)&sh[(el << 9) + (lane << 2)];
                const f32x4 xb = *(const f32x4*)&sh[(el << 9) + 256 + (lane << 2)];
                const f32x4 ha = *(const f32x4*)&sh1[(el << 9) + (lane << 2)];
                const f32x4 hb = *(const f32x4*)&sh1[(el << 9) + 256 + (lane << 2)];
#pragma unroll
                for (int r = 0; r < 4; ++r) {
                    float s = wx0[r][0] * xa[0];
                    s = fmaf(wx0[r][1], xa[1], s);
                    s = fmaf(wx0[r][2], xa[2], s);
                    s = fmaf(wx0[r][3], xa[3], s);
                    s = fmaf(wx1[r][0], xb[0], s);
                    s = fmaf(wx1[r][1], xb[1], s);
                    s = fmaf(wx1[r][2], xb[2], s);
                    s = fmaf(wx1[r][3], xb[3], s);
                    s = fmaf(wh0[r][0], ha[0], s);
                    s = fmaf(wh0[r][1], ha[1], s);
                    s = fmaf(wh0[r][2], ha[2], s);
                    s = fmaf(wh0[r][3], ha[3], s);
                    s = fmaf(wh1[r][0], hb[0], s);
                    s = fmaf(wh1[r][1], hb[1], s);
                    s = fmaf(wh1[r][2], hb[2], s);
                    s = fmaf(wh1[r][3], hb[3], s);
                    vvp[q][r] = s;
                }
                const float sum = reduce4(vvp[q], lane);
                const float hv = fast_tanh(sum + bias);
                if (lane < 4) {
                    coh_store(h1_ring + (((size_t)slot << 6) + eg0 + q) * 512 + rowbase + lane, hv);
                    if (t == sl4[q] - 1)
                        h1_final[((size_t)(eg0 + q) << 9) + rowbase + lane] = hv;
                }
            }
            vm_drain();
            __syncthreads();
            if (tid == 0) flag_store(myflag, (unsigned)(t + 1));
        }
    }
}

// ---- final head: y = Wyh[1] @ h1 + b_y[1]; out = Wf @ y + bf ----
__device__ __forceinline__ float dot4(float4 a, float4 b) {
    return fmaf(a.x, b.x, fmaf(a.y, b.y, fmaf(a.z, b.z, a.w * b.w)));
}
__device__ __forceinline__ float wave_reduce(float acc) {
#pragma unroll
    for (int off = 32; off > 0; off >>= 1) acc += __shfl_down(acc, off, 64);
    return acc;
}

__global__ __launch_bounds__(512) void head_kernel(
    const float* __restrict__ h1f, const float* __restrict__ Wyh,
    const float* __restrict__ b_y, const float* __restrict__ Wf,
    const float* __restrict__ bf, float* __restrict__ out)
{
    const int e = blockIdx.x;
    const int tid = threadIdx.x, wid = tid >> 6, lane = tid & 63;
    const int k0 = lane << 3;
    __shared__ float sh[H_];
    __shared__ float sy[H_];
    sh[tid] = h1f[(size_t)e * H_ + tid];
    __syncthreads();
    const float4 hA = *(const float4*)&sh[k0];
    const float4 hB = *(const float4*)&sh[k0 + 4];
    const float* Wy1 = Wyh + H_ * H_;
#pragma unroll 4
    for (int rr = 0; rr < 64; ++rr) {
        const int row = (wid << 6) + rr;
        float acc = wave_reduce(dot4(*(const float4*)&Wy1[(size_t)row * H_ + k0], hA) +
                                dot4(*(const float4*)&Wy1[(size_t)row * H_ + k0 + 4], hB));
        if (lane == 0) sy[row] = acc + b_y[H_ + row];
    }
    __syncthreads();
    const float4 yA = *(const float4*)&sy[k0];
    const float4 yB = *(const float4*)&sy[k0 + 4];
#pragma unroll
    for (int rr = 0; rr < 4; ++rr) {
        const int o = (wid << 2) + rr;
        float acc = wave_reduce(dot4(*(const float4*)&Wf[(size_t)o * H_ + k0], yA) +
                                dot4(*(const float4*)&Wf[(size_t)o * H_ + k0 + 4], yB));
        if (lane == 0) out[(size_t)e * O_ + o] = acc + bf[o];
    }
}

// ---- fallback (round-0, known-passing) ----
__global__ __launch_bounds__(1024, 1) void rnn_fused_fb(
    const int* __restrict__ x, const int* __restrict__ seq_lens,
    const float* __restrict__ emb, const float* __restrict__ Whx,
    const float* __restrict__ Whh, const float* __restrict__ b_h,
    const float* __restrict__ Wyh, const float* __restrict__ b_y,
    const float* __restrict__ Wf, const float* __restrict__ bf,
    float* __restrict__ out)
{
    const int b = blockIdx.x, tid = threadIdx.x;
    const int wave = tid >> 6, lane = tid & 63, k0 = lane << 3;
    __shared__ float s_inp[E_];
    __shared__ float s_h0[2][H_];
    __shared__ float s_h1[2][H_];
    __shared__ float s_y[H_];
    if (tid < H_) { s_h0[0][tid]=0.f; s_h0[1][tid]=0.f; s_h1[0][tid]=0.f; s_h1[1][tid]=0.f; }
    const int Tb = seq_lens[b];
    const float* Whx0 = Whx; const float* Whx1 = Whx + H_*E_;
    const float* Whh0 = Whh; const float* Whh1 = Whh + H_*H_;
    for (int t = 0; t < Tb; ++t) {
        const int cur = t & 1, prv = cur ^ 1;
        if (tid < E_) { const int tok = x[b*T_+t]; s_inp[tid] = emb[(size_t)tok*E_+tid]; }
        __syncthreads();
        const float4 iA = *(const float4*)&s_inp[k0], iB = *(const float4*)&s_inp[k0+4];
        const float4 pA = *(const float4*)&s_h0[prv][k0], pB = *(const float4*)&s_h0[prv][k0+4];
#pragma unroll 4
        for (int r = 0; r < 32; ++r) {
            const int i = (wave<<5)+r;
            float acc = dot4(*(const float4*)&Whx0[i*E_+k0], iA) + dot4(*(const float4*)&Whx0[i*E_+k0+4], iB)
                      + dot4(*(const float4*)&Whh0[i*H_+k0], pA) + dot4(*(const float4*)&Whh0[i*H_+k0+4], pB);
            acc = wave_reduce(acc);
            if (lane == 0) s_h0[cur][i] = tanhf(acc + b_h[i]);
        }
        __syncthreads();
        const float4 cA = *(const float4*)&s_h0[cur][k0], cB = *(const float4*)&s_h0[cur][k0+4];
        const float4 qA = *(const float4*)&s_h1[prv][k0], qB = *(const float4*)&s_h1[prv][k0+4];
#pragma unroll 4
        for (int r = 0; r < 32; ++r) {
            const int i = (wave<<5)+r;
            float acc = dot4(*(const float4*)&Whx1[i*E_+k0], cA) + dot4(*(const float4*)&Whx1[i*E_+k0+4], cB)
                      + dot4(*(const float4*)&Whh1[i*H_+k0], qA) + dot4(*(const float4*)&Whh1[i*H_+k0+4], qB);
            acc = wave_reduce(acc);
            if (lane == 0) s_h1[cur][i] = tanhf(acc + b_h[H_+i]);
        }
        __syncthreads();
    }
    const int lastb = (Tb-1) & 1;
    const float4 hA = *(const float4*)&s_h1[lastb][k0], hB = *(const float4*)&s_h1[lastb][k0+4];
    const float* Wy1 = Wyh + H_*H_;
#pragma unroll 4
    for (int r = 0; r < 32; ++r) {
        const int i = (wave<<5)+r;
        float acc = wave_reduce(dot4(*(const float4*)&Wy1[i*H_+k0], hA) + dot4(*(const float4*)&Wy1[i*H_+k0+4], hB));
        if (lane == 0) s_y[i] = acc + b_y[H_+i];
    }
    __syncthreads();
    const float4 yA = *(const float4*)&s_y[k0], yB = *(const float4*)&s_y[k0+4];
    if (wave < 8) {
#pragma unroll
        for (int r = 0; r < 4; ++r) {
            const int o = (wave<<2)+r;
            float acc = wave_reduce(dot4(*(const float4*)&Wf[o*H_+k0], yA) + dot4(*(const float4*)&Wf[o*H_+k0+4], yB));
            if (lane == 0) out[b*O_+o] = acc + bf[o];
        }
    }
}

extern "C" void kernel_launch(void* const* d_in, const int* in_sizes, int n_in,
                              void* d_out, int out_size, void* d_ws, size_t ws_size,
                              hipStream_t stream) {
    const int*   x    = (const int*)d_in[0];
    const int*   sl   = (const int*)d_in[1];
    const float* emb  = (const float*)d_in[2];
    const float* Whx  = (const float*)d_in[3];
    const float* Whh  = (const float*)d_in[4];
    const float* b_h  = (const float*)d_in[5];
    const float* Wyh  = (const float*)d_in[6];
    const float* b_y  = (const float*)d_in[7];
    const float* Wf   = (const float*)d_in[8];
    const float* bf   = (const float*)d_in[9];
    float* out = (float*)d_out;

    if (ws_size < WS_REQUIRED) {
        rnn_fused_fb<<<B_, 1024, 0, stream>>>(x, sl, emb, Whx, Whh, b_h, Wyh, b_y, Wf, bf, out);
        return;
    }

    float* ws_f = (float*)d_ws;
    float* h0_ring = ws_f + H0_OFF;
    float* h1_ring = ws_f + H1_OFF;
    float* h1f     = ws_f + HF_OFF;
    unsigned* flags = (unsigned*)(ws_f + FLAG_OFF);

    hipMemsetAsync(flags, 0, FLAG_UINTS * sizeof(unsigned), stream);
    rnn_pipe8<<<512, 512, 0, stream>>>(x, sl, emb, Whx, Whh, b_h,
                                       h0_ring, h1_ring, h1f, flags);
    head_kernel<<<B_, 512, 0, stream>>>(h1f, Wyh, b_y, Wf, bf, out);
}